// Round 5
// 264.568 us; speedup vs baseline: 1.0165x; 1.0165x over previous
//
#include <hip/hip_runtime.h>
#include <math.h>

// Problem constants
#define N_NODES 69
#define MP      80        // padded M (adjacency rows), 5 tiles of 16
#define KP      96        // padded K (adjacency cols), 3 tiles of 32
#define BT_TOTAL 32768
#define F_IN    8
#define H1      32
#define H2      16

#define TBT     8         // bt-instances per block
#define BLOCK   256       // 4 waves

#define ZPITCH  136       // Z plane: 128 cols + pad (u16)
#define HBPITCH 40        // Hb rows (was 32: 8-way bank conflict on H-pack writes)
#define RSTRIDE 72        // rows per bt in the flattened (bt,n) space
#define RROWS   576       // 8 * 72

typedef __attribute__((ext_vector_type(8))) short bf16x8;
typedef __attribute__((ext_vector_type(4))) float f32x4;

__device__ __forceinline__ unsigned short f2bf(float f) {
    unsigned u = __float_as_uint(f);
    return (unsigned short)((u + 0x7FFFu + ((u >> 16) & 1u)) >> 16);
}
__device__ __forceinline__ float bf2f(unsigned short h) {
    return __uint_as_float(((unsigned)h) << 16);
}

// ---------------------------------------------------------------------------
// Kernel 1 (round-0 verbatim): adjn split into bf16 hi+lo planes [MP][KP];
// W1/W2 pre-packed into MFMA B-fragment layout.
// ---------------------------------------------------------------------------
__global__ void setup_kernel(const float* __restrict__ adj,
                             const float* __restrict__ W1,
                             const float* __restrict__ W2,
                             unsigned short* __restrict__ adjh,
                             unsigned short* __restrict__ adjl,
                             unsigned short* __restrict__ W1p,  // [2][64][8]
                             unsigned short* __restrict__ W2p)  // [64][8]
{
    __shared__ float dinv[N_NODES];
    const int tid = threadIdx.x;
    if (tid < N_NODES) {
        float s = 1.0f;
        for (int j = 0; j < N_NODES; ++j) s += adj[tid * N_NODES + j];
        dinv[tid] = rsqrtf(s);
    }
    __syncthreads();
    for (int idx = tid; idx < MP * KP; idx += BLOCK) {
        const int n = idx / KP, m = idx % KP;
        float v = 0.0f;
        if (n < N_NODES && m < N_NODES) {
            float a = adj[n * N_NODES + m] + (n == m ? 1.0f : 0.0f);
            v = a * dinv[n] * dinv[m];
        }
        unsigned short h = f2bf(v);
        adjh[idx] = h;
        adjl[idx] = f2bf(v - bf2f(h));
    }
    // W1 B-frags for 2 N-tiles; K=8 lives entirely in quad 0 (rest zero)
    for (int i = tid; i < 2 * 64 * F_IN; i += BLOCK) {
        const int nt = i >> 9;
        const int ln = (i >> 3) & 63;
        const int j  = i & 7;
        const int q = ln >> 4, l = ln & 15;
        float v = (q == 0) ? W1[j * H1 + nt * 16 + l] : 0.0f;
        W1p[i] = f2bf(v);
    }
    // W2 B-frag; K=32 uses all quads (k = q*8 + j)
    for (int i = tid; i < 64 * F_IN; i += BLOCK) {
        const int ln = i >> 3, j = i & 7;
        const int q = ln >> 4, l = ln & 15;
        W2p[i] = f2bf(W2[(q * 8 + j) * H2 + l]);
    }
}

// ---------------------------------------------------------------------------
// Kernel 2.
//   P1 (NEW): Y1^T = X^T @ adjn. A-frags straight from global x (no LDS
//       staging); B-frags = rows of adjh/adjl via adjn symmetry (the exact
//       b128 pattern round 0 verified as its phase-1 A-loads). Output is
//       written to Y1_s with round-0's byte-identical formula, and wave wv
//       writes exactly rows [144*wv, 144*wv+144) -> round-0's no-barrier
//       property into phase 2 is preserved.
//   P2 (round-0 verbatim, Hb pitch 40): H = relu(Y1@W1); Z = H@W2.
//   P3 (round-0 verbatim): out = sigmoid(adjn @ Z).
// ---------------------------------------------------------------------------
__global__ __launch_bounds__(BLOCK, 4) void gcn_kernel(
    const float* __restrict__ x,              // [69][BT][8]
    const unsigned short* __restrict__ adjh,  // [80][96]
    const unsigned short* __restrict__ adjl,  // [80][96]
    const unsigned short* __restrict__ W1p,   // [2][64][8]
    const unsigned short* __restrict__ W2p,   // [64][8]
    float* __restrict__ out)                  // [BT][69][16]
{
    __shared__ unsigned short U_s[KP * ZPITCH];       // 26112 B (Z plane)
    __shared__ unsigned short Y1_s[RROWS * F_IN];     // 9216 B  [(bt*72+n)][f] bf16
    __shared__ unsigned short Hb_s[4][16 * HBPITCH];  // 5120 B  per-wave H tile
    // total 40448 B -> 4 blocks/CU

    const int tid  = threadIdx.x;
    const int lane = tid & 63;
    const int wv   = tid >> 6;
    const int quad = lane >> 4;
    const int l16  = lane & 15;
    const int bt0  = blockIdx.x * TBT;

    // ---- zero Z pad rows 69..95 (read by phase-3 B-gather; the single
    //      __syncthreads before phase 3 orders these vs all waves) ----
    for (int i = tid; i < 27 * 64; i += BLOCK) {
        const int row = N_NODES + (i >> 6), w = i & 63;
        ((unsigned*)U_s)[row * 68 + w] = 0u;
    }

    // ---- phase 1: Y1^T = X^T @ adjn -----------------------------------
    // A-tile rows = (bt,f): row l16 -> bt_local = l16>>3, f = l16&7.
    // A[l16][k=quad*8+j] = x[m = kt*32+quad*8+j][btg][f]  (m >= 69 -> 0)
    // B[k][n=l16] = adjn[n][k] (symmetry): 8 contiguous shorts of row n.
    // C: lane holds C[btf = quad*4+reg][n = nt*16+l16].
    const int btg = bt0 + wv * 2 + (l16 >> 3);
    const int fl  = l16 & 7;

    f32x4 acc[5] = {};
#pragma unroll
    for (int kt = 0; kt < 3; ++kt) {
        union AF { unsigned u[4]; bf16x8 v; } ah, al;
#pragma unroll
        for (int p = 0; p < 4; ++p) {
            const int m0 = kt * 32 + quad * 8 + 2 * p;
            const int m1 = m0 + 1;
            float x0 = 0.0f, x1 = 0.0f;
            if (kt < 2) {                       // m <= 63: always valid
                x0 = x[(size_t)m0 * 262144 + btg * 8 + fl];
                x1 = x[(size_t)m1 * 262144 + btg * 8 + fl];
            } else {                            // padded rows m >= 69 -> 0
                if (m0 < N_NODES) x0 = x[(size_t)m0 * 262144 + btg * 8 + fl];
                if (m1 < N_NODES) x1 = x[(size_t)m1 * 262144 + btg * 8 + fl];
            }
            const unsigned short h0 = f2bf(x0), h1 = f2bf(x1);
            ah.u[p] = (unsigned)h0 | ((unsigned)h1 << 16);
            const unsigned short g0 = f2bf(x0 - bf2f(h0));
            const unsigned short g1 = f2bf(x1 - bf2f(h1));
            al.u[p] = (unsigned)g0 | ((unsigned)g1 << 16);
        }
#pragma unroll
        for (int nt = 0; nt < 5; ++nt) {
            const int boff = (nt * 16 + l16) * KP + kt * 32 + quad * 8;
            const bf16x8 bh = *(const bf16x8*)(adjh + boff);
            const bf16x8 bl = *(const bf16x8*)(adjl + boff);
            acc[nt] = __builtin_amdgcn_mfma_f32_16x16x32_bf16(ah.v, bh, acc[nt], 0, 0, 0);
            acc[nt] = __builtin_amdgcn_mfma_f32_16x16x32_bf16(ah.v, bl, acc[nt], 0, 0, 0);
            acc[nt] = __builtin_amdgcn_mfma_f32_16x16x32_bf16(al.v, bh, acc[nt], 0, 0, 0);
        }
    }

    // Y1_s write: round-0's exact formula Y1_s[(btc*72 + n)*8 + fc].
    // btf-idx = quad*4+reg -> btc = wv*2 + (quad>>1), fc = (quad&1)*4 + reg.
    {
        const int btc = wv * 2 + (quad >> 1);
        const int fcb = (quad & 1) * 4;
#pragma unroll
        for (int nt = 0; nt < 5; ++nt) {
            const int n = nt * 16 + l16;
            if (n < RSTRIDE) {
#pragma unroll
                for (int reg = 0; reg < 4; ++reg)
                    Y1_s[(btc * RSTRIDE + n) * F_IN + fcb + reg] = f2bf(acc[nt][reg]);
            }
        }
    }
    // no barrier: wave wv wrote rows [144*wv, 144*wv+144) and reads only those

    // ---- W fragments (per-lane dwordx4, coalesced, L2-hot) ----
    const bf16x8 w1f0 = *(const bf16x8*)&W1p[lane * 8];
    const bf16x8 w1f1 = *(const bf16x8*)&W1p[(64 + lane) * 8];
    const bf16x8 w2f  = *(const bf16x8*)&W2p[lane * 8];

    // ---- phase 2 (round-0 verbatim, HBPITCH): H = relu(Y1@W1); Z = H@W2 ----
    unsigned short* Hb = Hb_s[wv];
#pragma unroll
    for (int mt2 = 0; mt2 < 9; ++mt2) {
        const int rb = wv * 144 + mt2 * 16;

        // A1 fragment: K=8 -> data only in quad 0, others zero
        bf16x8 af = {0, 0, 0, 0, 0, 0, 0, 0};
        if (quad == 0)
            af = *(const bf16x8*)&Y1_s[(rb + l16) * F_IN];

        f32x4 h0 = {0.f, 0.f, 0.f, 0.f};
        f32x4 h1 = {0.f, 0.f, 0.f, 0.f};
        h0 = __builtin_amdgcn_mfma_f32_16x16x32_bf16(af, w1f0, h0, 0, 0, 0);
        h1 = __builtin_amdgcn_mfma_f32_16x16x32_bf16(af, w1f1, h1, 0, 0, 0);

        // relu + pack C-layout -> Hb[m][h] (A-layout source for GEMM2)
#pragma unroll
        for (int reg = 0; reg < 4; ++reg) {
            const int row = quad * 4 + reg;
            Hb[row * HBPITCH + l16]      = f2bf(fmaxf(h0[reg], 0.f));
            Hb[row * HBPITCH + 16 + l16] = f2bf(fmaxf(h1[reg], 0.f));
        }
        // same-wave LDS dependency: compiler inserts lgkmcnt wait, no barrier
        const bf16x8 a2 = *(const bf16x8*)&Hb[l16 * HBPITCH + quad * 8];

        f32x4 zk = {0.f, 0.f, 0.f, 0.f};
        zk = __builtin_amdgcn_mfma_f32_16x16x32_bf16(a2, w2f, zk, 0, 0, 0);

        // scatter Z (C-layout) -> U_s[node][bt*16 + j]
#pragma unroll
        for (int reg = 0; reg < 4; ++reg) {
            const int r  = rb + quad * 4 + reg;
            const int bt = r / RSTRIDE;
            const int n  = r - bt * RSTRIDE;
            if (n < N_NODES)
                U_s[n * ZPITCH + bt * 16 + l16] = f2bf(zk[reg]);
        }
    }
    __syncthreads();

    // ---- phase 3 (round-0 verbatim): out = sigmoid(adjn @ Z) ----
#pragma unroll
    for (int c = 0; c < 2; ++c) {
        const int ct3  = wv * 2 + c;          // col tile == bt
        const int col3 = ct3 * 16 + l16;
        bf16x8 bz[3];
#pragma unroll
        for (int kt = 0; kt < 3; ++kt) {
            const int k0 = kt * 32 + quad * 8;
#pragma unroll
            for (int j = 0; j < 8; ++j)
                bz[kt][j] = (short)U_s[(k0 + j) * ZPITCH + col3];
        }
#pragma unroll
        for (int mt = 0; mt < 5; ++mt) {
            f32x4 acc3 = {0.f, 0.f, 0.f, 0.f};
#pragma unroll
            for (int kt = 0; kt < 3; ++kt) {
                const bf16x8 ah =
                    *(const bf16x8*)(adjh + (mt * 16 + l16) * KP + kt * 32 + quad * 8);
                acc3 = __builtin_amdgcn_mfma_f32_16x16x32_bf16(ah, bz[kt], acc3, 0, 0, 0);
            }
#pragma unroll
            for (int reg = 0; reg < 4; ++reg) {
                const int n = mt * 16 + quad * 4 + reg;
                if (n < N_NODES) {
                    const float v = 1.0f / (1.0f + __expf(-acc3[reg]));
                    out[((size_t)(bt0 + ct3) * N_NODES + n) * H2 + l16] = v;
                }
            }
        }
    }
}

// ---------------------------------------------------------------------------
extern "C" void kernel_launch(void* const* d_in, const int* in_sizes, int n_in,
                              void* d_out, int out_size, void* d_ws, size_t ws_size,
                              hipStream_t stream) {
    const float* x   = (const float*)d_in[0];
    const float* adj = (const float*)d_in[1];
    const float* W1  = (const float*)d_in[2];
    const float* W2  = (const float*)d_in[3];
    float* out = (float*)d_out;

    unsigned short* adjh = (unsigned short*)d_ws;       // 80*96
    unsigned short* adjl = adjh + MP * KP;              // 80*96
    unsigned short* W1p  = adjl + MP * KP;              // 2*64*8
    unsigned short* W2p  = W1p + 2 * 64 * F_IN;         // 64*8

    setup_kernel<<<1, BLOCK, 0, stream>>>(adj, W1, W2, adjh, adjl, W1p, W2p);
    gcn_kernel<<<BT_TOTAL / TBT, BLOCK, 0, stream>>>(x, adjh, adjl, W1p, W2p, out);
}